// Round 5
// baseline (194.600 us; speedup 1.0000x reference)
//
#include <hip/hip_runtime.h>
#include <cstdint>
#include <cstddef>

// Problem constants
#define SEQ 2048
#define HID 1024
#define NHEAD 16
#define HDIM 64

typedef _Float16 f16;
typedef f16 half8 __attribute__((ext_vector_type(8)));
typedef f16 half4 __attribute__((ext_vector_type(4)));
typedef f16 half2_ __attribute__((ext_vector_type(2)));
typedef float f32x4 __attribute__((ext_vector_type(4)));

// async global->LDS, 16B per lane (wave-uniform LDS base + lane*16)
#define ASYNC_COPY16(g, l)                                                    \
  __builtin_amdgcn_global_load_lds(                                           \
      (const __attribute__((address_space(1))) void*)(const void*)(g),        \
      (__attribute__((address_space(3))) void*)(void*)(l), 16, 0, 0)

// ---------------------------------------------------------------------------
// Prologue: transpose-cast weights. Blocks [0,3072): w_attn, [3072,4096): w_proj.
__global__ __launch_bounds__(256) void prologue(
    const float* __restrict__ wa, const float* __restrict__ wp,
    f16* __restrict__ waT, f16* __restrict__ wpT) {
  const int b = blockIdx.x, tid = threadIdx.x;
  const float* src; f16* dst; int C, bx, by;
  if (b < 3072) { src = wa; dst = waT; C = 3072; bx = b % 96; by = b / 96; }
  else { int t = b - 3072; src = wp; dst = wpT; C = 1024; bx = t & 31; by = t >> 5; }
  __shared__ float tile[32][33];
  const int tx = tid & 31, ty = tid >> 5;  // 32 x 8
  const int c0 = bx * 32, r0 = by * 32;
#pragma unroll
  for (int i = 0; i < 32; i += 8)
    tile[ty + i][tx] = src[(size_t)(r0 + ty + i) * C + c0 + tx];
  __syncthreads();
#pragma unroll
  for (int i = 0; i < 32; i += 8)
    dst[(size_t)(c0 + ty + i) * 1024 + r0 + tx] = (f16)tile[tx][ty + i];
}

// ---------------------------------------------------------------------------
// V transpose: qkv V-part [s][h*64+d] -> Vt[h][d][s]. 32x32 f16 tiles.
__global__ __launch_bounds__(256) void vtrans(const f16* __restrict__ qkv,
                                              f16* __restrict__ Vt) {
  const int b = blockIdx.x, tid = threadIdx.x;
  const int h = b >> 7, t = b & 127;
  const int s0 = (t >> 1) * 32, d0 = (t & 1) * 32;
  __shared__ f16 tile[32][33];
  const int tx = tid & 31, ty = tid >> 5;
#pragma unroll
  for (int i = 0; i < 32; i += 8)
    tile[ty + i][tx] =
        qkv[(size_t)(s0 + ty + i) * 3072 + 2 * HID + h * HDIM + d0 + tx];
  __syncthreads();
#pragma unroll
  for (int i = 0; i < 32; i += 8)
    Vt[(size_t)h * HDIM * SEQ + (size_t)(d0 + ty + i) * SEQ + s0 + tx] =
        tile[tx][ty + i];
}

// ---------------------------------------------------------------------------
// C = A * Bt^T + bias ; BM x BN tile, BK=32, 4 waves as 2x2.
// AF32: A is fp32, cast during manual staging (requires BM=128).
template <int BM, int BN, bool OUT16, bool AF32>
__global__ __launch_bounds__(256) void gemm_f16(
    const void* __restrict__ Ap, const f16* __restrict__ Bt,
    const float* __restrict__ bias, void* __restrict__ Cout, int M, int N,
    int K) {
  constexpr int FM = BM / 32, FN = BN / 32;
  __shared__ __align__(16) f16 sA[BM * 32];
  __shared__ __align__(16) f16 sB[BN * 32];
  const int tid = threadIdx.x;
  const int wave = tid >> 6, lane = tid & 63;
  const int quad = lane >> 4, l16 = lane & 15;
  const int m0 = blockIdx.y * BM, n0 = blockIdx.x * BN;
  const int wm = (wave >> 1) * (BM / 2), wn = (wave & 1) * (BN / 2);
  const int rowA = lane >> 2, chunkA = lane & 3;

  f32x4 acc[FM][FN] = {};

  for (int k0 = 0; k0 < K; k0 += 32) {
    if (AF32) {
      // A fp32 -> f16 staging: thread covers 16 k of one row
      const int row = tid >> 1, kh = (tid & 1) * 16;
      const float* p = (const float*)Ap + (size_t)(m0 + row) * K + k0 + kh;
      float4 a0 = ((const float4*)p)[0], a1 = ((const float4*)p)[1];
      float4 a2 = ((const float4*)p)[2], a3 = ((const float4*)p)[3];
      half8 h0, h1;
      h0[0] = (f16)a0.x; h0[1] = (f16)a0.y; h0[2] = (f16)a0.z; h0[3] = (f16)a0.w;
      h0[4] = (f16)a1.x; h0[5] = (f16)a1.y; h0[6] = (f16)a1.z; h0[7] = (f16)a1.w;
      h1[0] = (f16)a2.x; h1[1] = (f16)a2.y; h1[2] = (f16)a2.z; h1[3] = (f16)a2.w;
      h1[4] = (f16)a3.x; h1[5] = (f16)a3.y; h1[6] = (f16)a3.z; h1[7] = (f16)a3.w;
      *(half8*)&sA[row * 32 + kh] = h0;
      *(half8*)&sA[row * 32 + kh + 8] = h1;
    } else {
      const f16* A = (const f16*)Ap;
#pragma unroll
      for (int r = wave; r < BM / 16; r += 4)
        ASYNC_COPY16(A + (size_t)(m0 + r * 16 + rowA) * K + k0 + chunkA * 8,
                     &sA[r * 512]);
    }
#pragma unroll
    for (int r = wave; r < BN / 16; r += 4)
      ASYNC_COPY16(Bt + (size_t)(n0 + r * 16 + rowA) * K + k0 + chunkA * 8,
                   &sB[r * 512]);
    __syncthreads();

    half8 af[FM], bf[FN];
#pragma unroll
    for (int i = 0; i < FM; i++)
      af[i] = *(const half8*)&sA[(wm + i * 16 + l16) * 32 + quad * 8];
#pragma unroll
    for (int j = 0; j < FN; j++)
      bf[j] = *(const half8*)&sB[(wn + j * 16 + l16) * 32 + quad * 8];
#pragma unroll
    for (int i = 0; i < FM; i++)
#pragma unroll
      for (int j = 0; j < FN; j++)
        acc[i][j] = __builtin_amdgcn_mfma_f32_16x16x32_f16(af[i], bf[j],
                                                           acc[i][j], 0, 0, 0);
    __syncthreads();
  }

#pragma unroll
  for (int i = 0; i < FM; i++) {
    int row = m0 + wm + i * 16 + quad * 4;
#pragma unroll
    for (int j = 0; j < FN; j++) {
      int col = n0 + wn + j * 16 + l16;
      float bv = bias[col];
#pragma unroll
      for (int r = 0; r < 4; r++) {
        float v = acc[i][j][r] + bv;
        if (OUT16)
          ((f16*)Cout)[(size_t)(row + r) * N + col] = (f16)v;
        else
          ((float*)Cout)[(size_t)(row + r) * N + col] = v;
      }
    }
  }
}

// ---------------------------------------------------------------------------
// Split-K causal flash attention, transposed-S, BARRIER-FREE.
// K-frags and V^T-frags read directly from global (L1-served; both are
// contiguous 16B/lane in the transposed-S formulation). Only LDS use is the
// wave-private P C-layout -> B-layout round trip. Zero __syncthreads.
// 32 q-rows per wave (2 groups of 16 sharing K/V frags). 128 q-rows/block.
// Grid: 16 heads x 40 (m,chunk) = 640 blocks.
#define LROW 72
__global__ __launch_bounds__(256) void attn_split(
    const f16* __restrict__ qkv, const f16* __restrict__ Vt,
    f16* __restrict__ out, f16* __restrict__ Opart, float* __restrict__ ml) {
  const int b = blockIdx.x;
  const int h = b / 40;
  const int t = b % 40;
  int m, c, nc;
  if (t < 4)       { m = t;                 c = 0;      nc = 1; }
  else if (t < 12) { int u = t - 4;  m = 4 + (u >> 1);  c = u & 1; nc = 2; }
  else if (t < 24) { int u = t - 12; m = 8 + u / 3;     c = u % 3; nc = 3; }
  else             { int u = t - 24; m = 12 + (u >> 2); c = u & 3; nc = 4; }
  const int q0 = m * 128;
  const int T = 2 * m + 2;
  const int kt0 = c * 8;
  const int kt1 = (kt0 + 8 < T) ? kt0 + 8 : T;
  const int maskFrom = 2 * m;

  __shared__ __align__(16) f16 sP[4][32 * LROW];  // per-wave P[q][k]

  const int tid = threadIdx.x;
  const int wave = tid >> 6, lane = tid & 63;
  const int quad = lane >> 4, l16 = lane & 15;

  // Q fragments (MFMA B operand), pre-scaled by sm_scale*log2(e)
  const f16 qs = (f16)0.18033688f;  // 0.125 * log2(e)
  half8 qf[2][2];
#pragma unroll
  for (int g = 0; g < 2; g++) {
    const f16* qb = qkv + (size_t)(q0 + wave * 32 + g * 16 + l16) * 3072 +
                    h * HDIM + quad * 8;
    qf[g][0] = *(const half8*)qb;
    qf[g][1] = *(const half8*)(qb + 32);
#pragma unroll
    for (int j = 0; j < 8; j++) { qf[g][0][j] *= qs; qf[g][1][j] *= qs; }
  }

  const f16* kbase = qkv + HID + h * HDIM;
  const f16* vtb = Vt + (size_t)h * HDIM * SEQ;

  f32x4 o[2][4] = {};
  float m_i[2] = {-1e30f, -1e30f}, l_i[2] = {0.f, 0.f};

  for (int kt = kt0; kt < kt1; kt++) {
    const int k0 = kt * 64;

    // S^T = K Q^T ; K-frags direct from global (A-operand: 16B contiguous)
    f32x4 sacc[2][4] = {};
#pragma unroll
    for (int kb = 0; kb < 4; kb++) {
      const f16* kp = kbase + (size_t)(k0 + kb * 16 + l16) * 3072 + quad * 8;
      half8 kf0 = *(const half8*)kp;
      half8 kf1 = *(const half8*)(kp + 32);
#pragma unroll
      for (int g = 0; g < 2; g++) {
        sacc[g][kb] = __builtin_amdgcn_mfma_f32_16x16x32_f16(kf0, qf[g][0],
                                                             sacc[g][kb], 0, 0, 0);
        sacc[g][kb] = __builtin_amdgcn_mfma_f32_16x16x32_f16(kf1, qf[g][1],
                                                             sacc[g][kb], 0, 0, 0);
      }
    }
    // V^T-frags direct from Vt (issued early, in flight during softmax)
    half8 vf[4][2];
#pragma unroll
    for (int j = 0; j < 4; j++) {
      const f16* vp = vtb + (size_t)(j * 16 + l16) * SEQ + k0 + quad * 8;
      vf[j][0] = *(const half8*)vp;
      vf[j][1] = *(const half8*)(vp + 32);
    }
    // causal mask on diagonal-overlap tiles
    if (kt >= maskFrom) {
#pragma unroll
      for (int g = 0; g < 2; g++) {
        const int qg = q0 + wave * 32 + g * 16 + l16;
#pragma unroll
        for (int kb = 0; kb < 4; kb++) {
          int kg = k0 + kb * 16 + quad * 4;
#pragma unroll
          for (int r = 0; r < 4; r++)
            if (kg + r > qg) sacc[g][kb][r] = -1e30f;
        }
      }
    }
    // online softmax per q-group (lane owns one q-column per group)
#pragma unroll
    for (int g = 0; g < 2; g++) {
      float mx = -1e30f;
#pragma unroll
      for (int kb = 0; kb < 4; kb++)
#pragma unroll
        for (int r = 0; r < 4; r++) mx = fmaxf(mx, sacc[g][kb][r]);
      mx = fmaxf(mx, __shfl_xor(mx, 16));
      mx = fmaxf(mx, __shfl_xor(mx, 32));
      const float mnew = fmaxf(m_i[g], mx);
      const float alpha = exp2f(m_i[g] - mnew);
      float rs = 0.f;
#pragma unroll
      for (int kb = 0; kb < 4; kb++)
#pragma unroll
        for (int r = 0; r < 4; r++) {
          float p = exp2f(sacc[g][kb][r] - mnew);
          sacc[g][kb][r] = p;
          rs += p;
        }
      rs += __shfl_xor(rs, 16);
      rs += __shfl_xor(rs, 32);
      l_i[g] = l_i[g] * alpha + rs;
      m_i[g] = mnew;
#pragma unroll
      for (int j = 0; j < 4; j++)
#pragma unroll
        for (int r = 0; r < 4; r++) o[g][j][r] *= alpha;
      // P: C-layout -> wave-private LDS (in-order within wave, no barrier)
      f16* pw = &sP[wave][(g * 16 + l16) * LROW];
#pragma unroll
      for (int kb = 0; kb < 4; kb++)
#pragma unroll
        for (int rp = 0; rp < 2; rp++) {
          half2_ pv;
          pv[0] = (f16)sacc[g][kb][rp * 2];
          pv[1] = (f16)sacc[g][kb][rp * 2 + 1];
          *(half2_*)&pw[kb * 16 + quad * 4 + rp * 2] = pv;
        }
    }
    // O^T += V^T P^T
#pragma unroll
    for (int j = 0; j < 4; j++) {
#pragma unroll
      for (int g = 0; g < 2; g++) {
        half8 pf0 = *(const half8*)&sP[wave][(g * 16 + l16) * LROW + quad * 8];
        half8 pf1 =
            *(const half8*)&sP[wave][(g * 16 + l16) * LROW + 32 + quad * 8];
        o[g][j] = __builtin_amdgcn_mfma_f32_16x16x32_f16(vf[j][0], pf0,
                                                         o[g][j], 0, 0, 0);
        o[g][j] = __builtin_amdgcn_mfma_f32_16x16x32_f16(vf[j][1], pf1,
                                                         o[g][j], 0, 0, 0);
      }
    }
  }

  if (nc == 1) {
#pragma unroll
    for (int g = 0; g < 2; g++) {
      const float inv = 1.f / l_i[g];
      f16* orow =
          out + (size_t)(q0 + wave * 32 + g * 16 + l16) * HID + h * HDIM;
#pragma unroll
      for (int j = 0; j < 4; j++) {
        half4 hv;
#pragma unroll
        for (int r = 0; r < 4; r++) hv[r] = (f16)(o[g][j][r] * inv);
        *(half4*)&orow[j * 16 + quad * 4] = hv;
      }
    }
  } else {
    int base;
    if (m < 8)       base = (m - 4) * 2;
    else if (m < 12) base = 8 + (m - 8) * 3;
    else             base = 20 + (m - 12) * 4;
    const int slot = h * 36 + base + c;
#pragma unroll
    for (int g = 0; g < 2; g++) {
      const int qrow = wave * 32 + g * 16 + l16;
      f16* op = Opart + (size_t)slot * 8192 + qrow * 64;
#pragma unroll
      for (int j = 0; j < 4; j++) {
        half4 hv;
#pragma unroll
        for (int r = 0; r < 4; r++) hv[r] = (f16)o[g][j][r];
        *(half4*)&op[j * 16 + quad * 4] = hv;
      }
      if (quad == 0) {
        ml[slot * 256 + qrow] = m_i[g];
        ml[slot * 256 + 128 + qrow] = l_i[g];
      }
    }
  }
}

// ---------------------------------------------------------------------------
// Combine partials for m >= 4. One thread per (head, m, row, d).
__global__ __launch_bounds__(256) void attn_combine(
    const f16* __restrict__ Opart, const float* __restrict__ ml,
    f16* __restrict__ out) {
  int idx = blockIdx.x * 256 + threadIdx.x;
  int d = idx & 63;
  int row = (idx >> 6) & 127;
  int rest = idx >> 13;      // 0..191
  int mi = rest % 12;        // m-4
  int h = rest / 12;
  int m = 4 + mi;
  int nc = (mi < 4) ? 2 : (mi < 8) ? 3 : 4;
  int base = (mi < 4) ? mi * 2 : (mi < 8) ? 8 + (mi - 4) * 3 : 20 + (mi - 8) * 4;
  int slot0 = h * 36 + base;

  float mm[4], ll[4];
  float M = -1e30f;
  for (int cc = 0; cc < nc; cc++) {
    mm[cc] = ml[(slot0 + cc) * 256 + row];
    ll[cc] = ml[(slot0 + cc) * 256 + 128 + row];
    M = fmaxf(M, mm[cc]);
  }
  float L = 0.f, acc = 0.f;
  for (int cc = 0; cc < nc; cc++) {
    float w = exp2f(mm[cc] - M);
    L += w * ll[cc];
    acc += w * (float)Opart[(size_t)(slot0 + cc) * 8192 + row * 64 + d];
  }
  out[(size_t)(m * 128 + row) * HID + h * HDIM + d] = (f16)(acc / L);
}

// ---------------------------------------------------------------------------
extern "C" void kernel_launch(void* const* d_in, const int* in_sizes, int n_in,
                              void* d_out, int out_size, void* d_ws,
                              size_t ws_size, hipStream_t stream) {
  const float* h = (const float*)d_in[0];    // [2048,1024]
  const float* wa = (const float*)d_in[1];   // [1024,3072]
  const float* ba = (const float*)d_in[2];   // [3072]
  const float* wp = (const float*)d_in[3];   // [1024,1024]
  const float* bp = (const float*)d_in[4];   // [1024]
  float* out = (float*)d_out;                // [2048,1024] fp32

  char* ws = (char*)d_ws;
  f16* waT = (f16*)(ws);                       //  6 MiB [3072][1024]
  f16* wpT = (f16*)(ws + (6u << 20));          //  2 MiB [1024][1024]
  f16* qkv = (f16*)(ws + (8u << 20));          // 12 MiB [2048][3072]
  f16* Vt = (f16*)(ws + (20u << 20));          //  4 MiB [16][64][2048]
  f16* attn = (f16*)(ws + (24u << 20));        //  4 MiB [2048][1024]
  f16* Opart = (f16*)(ws + (28u << 20));       // 576*8192*2 = 9.44 MB
  float* mlbuf = (float*)(ws + (28u << 20) + 9437184);  // 576*256*4

  prologue<<<4096, 256, 0, stream>>>(wa, wp, waT, wpT);
  // QKV = H @ Wattn + b -> f16 (fp32 A cast fused into staging)
  gemm_f16<128, 128, true, true><<<dim3(24, 16), 256, 0, stream>>>(
      h, waT, ba, qkv, SEQ, 3 * HID, HID);
  // one-time V transpose for direct V^T fragment loads
  vtrans<<<2048, 256, 0, stream>>>(qkv, Vt);
  // barrier-free split-K causal attention + combine
  attn_split<<<640, 256, 0, stream>>>(qkv, Vt, attn, Opart, mlbuf);
  attn_combine<<<6144, 256, 0, stream>>>(Opart, mlbuf, attn);
  // OUT = attn @ Wproj + b -> fp32
  gemm_f16<64, 64, false, false><<<dim3(16, 32), 256, 0, stream>>>(
      attn, wpT, bp, out, SEQ, HID, HID);
}

// Round 6
// 176.271 us; speedup vs baseline: 1.1040x; 1.1040x over previous
//
#include <hip/hip_runtime.h>
#include <cstdint>
#include <cstddef>

// Problem constants
#define SEQ 2048
#define HID 1024
#define NHEAD 16
#define HDIM 64

typedef _Float16 f16;
typedef f16 half8 __attribute__((ext_vector_type(8)));
typedef f16 half4 __attribute__((ext_vector_type(4)));
typedef float f32x4 __attribute__((ext_vector_type(4)));

// async global->LDS, 16B per lane (wave-uniform LDS base + lane*16)
#define ASYNC_COPY16(g, l)                                                    \
  __builtin_amdgcn_global_load_lds(                                           \
      (const __attribute__((address_space(1))) void*)(const void*)(g),        \
      (__attribute__((address_space(3))) void*)(void*)(l), 16, 0, 0)

// ---------------------------------------------------------------------------
// Prologue: transpose-cast weights. Blocks [0,3072): w_attn, [3072,4096): w_proj.
__global__ __launch_bounds__(256) void prologue(
    const float* __restrict__ wa, const float* __restrict__ wp,
    f16* __restrict__ waT, f16* __restrict__ wpT) {
  const int b = blockIdx.x, tid = threadIdx.x;
  const float* src; f16* dst; int C, bx, by;
  if (b < 3072) { src = wa; dst = waT; C = 3072; bx = b % 96; by = b / 96; }
  else { int t = b - 3072; src = wp; dst = wpT; C = 1024; bx = t & 31; by = t >> 5; }
  __shared__ float tile[32][33];
  const int tx = tid & 31, ty = tid >> 5;  // 32 x 8
  const int c0 = bx * 32, r0 = by * 32;
#pragma unroll
  for (int i = 0; i < 32; i += 8)
    tile[ty + i][tx] = src[(size_t)(r0 + ty + i) * C + c0 + tx];
  __syncthreads();
#pragma unroll
  for (int i = 0; i < 32; i += 8)
    dst[(size_t)(c0 + ty + i) * 1024 + r0 + tx] = (f16)tile[tx][ty + i];
}

// ---------------------------------------------------------------------------
// C = A * Bt^T + bias ; BM x BN tile, two BK=32 sub-tiles per barrier pair
// (K-step 64, m97-verified LDS layout per sub-tile, half the barrier drains).
// AF32: A is fp32, cast fused into staging (requires BM=128).
template <int BM, int BN, bool OUT16, bool AF32>
__global__ __launch_bounds__(256) void gemm_f16(
    const void* __restrict__ Ap, const f16* __restrict__ Bt,
    const float* __restrict__ bias, void* __restrict__ Cout, int M, int N,
    int K) {
  constexpr int FM = BM / 32, FN = BN / 32;
  __shared__ __align__(16) f16 sA[2][BM * 32];
  __shared__ __align__(16) f16 sB[2][BN * 32];
  const int tid = threadIdx.x;
  const int wave = tid >> 6, lane = tid & 63;
  const int quad = lane >> 4, l16 = lane & 15;
  const int m0 = blockIdx.y * BM, n0 = blockIdx.x * BN;
  const int wm = (wave >> 1) * (BM / 2), wn = (wave & 1) * (BN / 2);
  const int rowA = lane >> 2, chunkA = lane & 3;

  f32x4 acc[FM][FN] = {};

  for (int k0 = 0; k0 < K; k0 += 64) {
    if (AF32) {
      // A fp32 -> f16 staging: thread covers 16 k of one row per sub-tile
      const int row = tid >> 1, kh = (tid & 1) * 16;
      const float* p0 = (const float*)Ap + (size_t)(m0 + row) * K + k0 + kh;
#pragma unroll
      for (int tt = 0; tt < 2; tt++) {
        const float* p = p0 + tt * 32;
        float4 a0 = ((const float4*)p)[0], a1 = ((const float4*)p)[1];
        float4 a2 = ((const float4*)p)[2], a3 = ((const float4*)p)[3];
        half8 h0, h1;
        h0[0] = (f16)a0.x; h0[1] = (f16)a0.y; h0[2] = (f16)a0.z; h0[3] = (f16)a0.w;
        h0[4] = (f16)a1.x; h0[5] = (f16)a1.y; h0[6] = (f16)a1.z; h0[7] = (f16)a1.w;
        h1[0] = (f16)a2.x; h1[1] = (f16)a2.y; h1[2] = (f16)a2.z; h1[3] = (f16)a2.w;
        h1[4] = (f16)a3.x; h1[5] = (f16)a3.y; h1[6] = (f16)a3.z; h1[7] = (f16)a3.w;
        *(half8*)&sA[tt][row * 32 + kh] = h0;
        *(half8*)&sA[tt][row * 32 + kh + 8] = h1;
      }
    } else {
      const f16* A = (const f16*)Ap;
#pragma unroll
      for (int tt = 0; tt < 2; tt++)
#pragma unroll
        for (int r = wave; r < BM / 16; r += 4)
          ASYNC_COPY16(
              A + (size_t)(m0 + r * 16 + rowA) * K + k0 + tt * 32 + chunkA * 8,
              &sA[tt][r * 512]);
    }
#pragma unroll
    for (int tt = 0; tt < 2; tt++)
#pragma unroll
      for (int r = wave; r < BN / 16; r += 4)
        ASYNC_COPY16(
            Bt + (size_t)(n0 + r * 16 + rowA) * K + k0 + tt * 32 + chunkA * 8,
            &sB[tt][r * 512]);
    __syncthreads();

#pragma unroll
    for (int tt = 0; tt < 2; tt++) {
      half8 af[FM], bf[FN];
#pragma unroll
      for (int i = 0; i < FM; i++)
        af[i] = *(const half8*)&sA[tt][(wm + i * 16 + l16) * 32 + quad * 8];
#pragma unroll
      for (int j = 0; j < FN; j++)
        bf[j] = *(const half8*)&sB[tt][(wn + j * 16 + l16) * 32 + quad * 8];
#pragma unroll
      for (int i = 0; i < FM; i++)
#pragma unroll
        for (int j = 0; j < FN; j++)
          acc[i][j] = __builtin_amdgcn_mfma_f32_16x16x32_f16(af[i], bf[j],
                                                             acc[i][j], 0, 0, 0);
    }
    __syncthreads();
  }

#pragma unroll
  for (int i = 0; i < FM; i++) {
    int row = m0 + wm + i * 16 + quad * 4;
#pragma unroll
    for (int j = 0; j < FN; j++) {
      int col = n0 + wn + j * 16 + l16;
      float bv = bias[col];
#pragma unroll
      for (int r = 0; r < 4; r++) {
        float v = acc[i][j][r] + bv;
        if (OUT16)
          ((f16*)Cout)[(size_t)(row + r) * N + col] = (f16)v;
        else
          ((float*)Cout)[(size_t)(row + r) * N + col] = v;
      }
    }
  }
}

// ---------------------------------------------------------------------------
// Split-K causal flash attention (r4 staged structure, chunk=4).
// Transposed-S: lane owns one q-column; 32 q-rows/wave (2 groups share K/V
// frags). 128 q-rows/block. Grid: 16 heads x 72 (m,chunk) = 1152 blocks.
#define LROW 72
__global__ __launch_bounds__(256, 3) void attn_split(
    const f16* __restrict__ qkv, f16* __restrict__ out,
    f16* __restrict__ Opart, float* __restrict__ ml) {
  const int b = blockIdx.x;
  const int h = b / 72;
  const int t = b % 72;
  int m, c, nc, base = 0;
  if (t < 2) { m = t; c = 0; nc = 1; }
  else {
    int s = t - 2, acc = 0;
    m = 2; c = 0; nc = 2;
    for (int mm = 2; mm <= 15; mm++) {
      int n = (2 * mm + 5) >> 2;  // ceil((2m+2)/4)
      if (s < acc + n) { m = mm; c = s - acc; nc = n; base = acc; break; }
      acc += n;
    }
  }
  const int q0 = m * 128;
  const int T = 2 * m + 2;             // k64 tiles (causal)
  const int kt0 = c * 4;
  const int kt1 = (kt0 + 4 < T) ? kt0 + 4 : T;
  const int maskFrom = 2 * m;

  __shared__ __align__(16) f16 sK[64 * LROW];      // [s_k][d]
  __shared__ __align__(16) f16 sVt[64 * LROW];     // [d][s_k]
  __shared__ __align__(16) f16 sP[4][32 * LROW];   // per-wave P[q][k]

  const int tid = threadIdx.x;
  const int wave = tid >> 6, lane = tid & 63;
  const int quad = lane >> 4, l16 = lane & 15;

  // Q fragments (MFMA B operand), pre-scaled by sm_scale*log2(e)
  const f16 qs = (f16)0.18033688f;  // 0.125 * log2(e)
  half8 qf[2][2];
#pragma unroll
  for (int g = 0; g < 2; g++) {
    const f16* qb = qkv + (size_t)(q0 + wave * 32 + g * 16 + l16) * 3072 +
                    h * HDIM + quad * 8;
    qf[g][0] = *(const half8*)qb;
    qf[g][1] = *(const half8*)(qb + 32);
#pragma unroll
    for (int j = 0; j < 8; j++) { qf[g][0][j] *= qs; qf[g][1][j] *= qs; }
  }

  const f16* kbase = qkv + HID + h * HDIM;
  const f16* vbase = qkv + 2 * HID + h * HDIM;
  const int ks_row = tid >> 3, ks_cc = tid & 7;
  const int vs_d = tid & 63, vs_g = tid >> 6;

  f32x4 o[2][4] = {};
  float m_i[2] = {-1e30f, -1e30f}, l_i[2] = {0.f, 0.f};
  half8 kreg[2], vreg[2];

  auto prefetch = [&](int kt) {
    const int k0 = kt * 64;
#pragma unroll
    for (int i = 0; i < 2; i++) {
      kreg[i] = *(const half8*)(kbase + (size_t)(k0 + ks_row + i * 32) * 3072 +
                                ks_cc * 8);
      half8 col;
#pragma unroll
      for (int j = 0; j < 8; j++)
        col[j] = vbase[(size_t)(k0 + (vs_g + i * 4) * 8 + j) * 3072 + vs_d];
      vreg[i] = col;
    }
  };

  prefetch(kt0);
  for (int kt = kt0; kt < kt1; kt++) {
    const int k0 = kt * 64;
#pragma unroll
    for (int i = 0; i < 2; i++) {
      *(half8*)&sK[(ks_row + i * 32) * LROW + ks_cc * 8] = kreg[i];
      *(half8*)&sVt[vs_d * LROW + (vs_g + i * 4) * 8] = vreg[i];
    }
    __syncthreads();
    if (kt + 1 < kt1) prefetch(kt + 1);

    // S^T = K Q^T ; K-frag reads shared across both q-groups
    f32x4 sacc[2][4] = {};
#pragma unroll
    for (int kb = 0; kb < 4; kb++) {
      half8 kf0 = *(const half8*)&sK[(kb * 16 + l16) * LROW + quad * 8];
      half8 kf1 = *(const half8*)&sK[(kb * 16 + l16) * LROW + 32 + quad * 8];
#pragma unroll
      for (int g = 0; g < 2; g++) {
        sacc[g][kb] = __builtin_amdgcn_mfma_f32_16x16x32_f16(kf0, qf[g][0],
                                                             sacc[g][kb], 0, 0, 0);
        sacc[g][kb] = __builtin_amdgcn_mfma_f32_16x16x32_f16(kf1, qf[g][1],
                                                             sacc[g][kb], 0, 0, 0);
      }
    }
    // causal mask on diagonal-overlap tiles
    if (kt >= maskFrom) {
#pragma unroll
      for (int g = 0; g < 2; g++) {
        const int qg = q0 + wave * 32 + g * 16 + l16;
#pragma unroll
        for (int kb = 0; kb < 4; kb++) {
          int kg = k0 + kb * 16 + quad * 4;
#pragma unroll
          for (int r = 0; r < 4; r++)
            if (kg + r > qg) sacc[g][kb][r] = -1e30f;
        }
      }
    }
    // online softmax per q-group (lane owns one q-column per group)
#pragma unroll
    for (int g = 0; g < 2; g++) {
      float mx = -1e30f;
#pragma unroll
      for (int kb = 0; kb < 4; kb++)
#pragma unroll
        for (int r = 0; r < 4; r++) mx = fmaxf(mx, sacc[g][kb][r]);
      mx = fmaxf(mx, __shfl_xor(mx, 16));
      mx = fmaxf(mx, __shfl_xor(mx, 32));
      const float mnew = fmaxf(m_i[g], mx);
      const float alpha = exp2f(m_i[g] - mnew);
      float rs = 0.f;
#pragma unroll
      for (int kb = 0; kb < 4; kb++)
#pragma unroll
        for (int r = 0; r < 4; r++) {
          float p = exp2f(sacc[g][kb][r] - mnew);
          sacc[g][kb][r] = p;
          rs += p;
        }
      rs += __shfl_xor(rs, 16);
      rs += __shfl_xor(rs, 32);
      l_i[g] = l_i[g] * alpha + rs;
      m_i[g] = mnew;
#pragma unroll
      for (int j = 0; j < 4; j++)
#pragma unroll
        for (int r = 0; r < 4; r++) o[g][j][r] *= alpha;
      // P store: one b64 per kb (quad*4 consecutive k values)
      f16* pw = &sP[wave][(g * 16 + l16) * LROW];
#pragma unroll
      for (int kb = 0; kb < 4; kb++) {
        half4 pv;
#pragma unroll
        for (int r = 0; r < 4; r++) pv[r] = (f16)sacc[g][kb][r];
        *(half4*)&pw[kb * 16 + quad * 4] = pv;
      }
    }
    // O^T += V^T P^T ; V-frag reads shared across both q-groups
#pragma unroll
    for (int j = 0; j < 4; j++) {
      half8 vf0 = *(const half8*)&sVt[(j * 16 + l16) * LROW + quad * 8];
      half8 vf1 = *(const half8*)&sVt[(j * 16 + l16) * LROW + 32 + quad * 8];
#pragma unroll
      for (int g = 0; g < 2; g++) {
        half8 pf0 = *(const half8*)&sP[wave][(g * 16 + l16) * LROW + quad * 8];
        half8 pf1 =
            *(const half8*)&sP[wave][(g * 16 + l16) * LROW + 32 + quad * 8];
        o[g][j] = __builtin_amdgcn_mfma_f32_16x16x32_f16(vf0, pf0, o[g][j], 0, 0, 0);
        o[g][j] = __builtin_amdgcn_mfma_f32_16x16x32_f16(vf1, pf1, o[g][j], 0, 0, 0);
      }
    }
    __syncthreads();
  }

  if (nc == 1) {
#pragma unroll
    for (int g = 0; g < 2; g++) {
      const float inv = 1.f / l_i[g];
      f16* orow =
          out + (size_t)(q0 + wave * 32 + g * 16 + l16) * HID + h * HDIM;
#pragma unroll
      for (int j = 0; j < 4; j++) {
        half4 hv;
#pragma unroll
        for (int r = 0; r < 4; r++) hv[r] = (f16)(o[g][j][r] * inv);
        *(half4*)&orow[j * 16 + quad * 4] = hv;
      }
    }
  } else {
    const int slot = h * 70 + base + c;  // 70 multi-chunk slots per head
#pragma unroll
    for (int g = 0; g < 2; g++) {
      const int qrow = wave * 32 + g * 16 + l16;
      f16* op = Opart + (size_t)slot * 8192 + qrow * 64;
#pragma unroll
      for (int j = 0; j < 4; j++) {
        half4 hv;
#pragma unroll
        for (int r = 0; r < 4; r++) hv[r] = (f16)o[g][j][r];
        *(half4*)&op[j * 16 + quad * 4] = hv;
      }
      if (quad == 0) {
        ml[slot * 256 + qrow] = m_i[g];
        ml[slot * 256 + 128 + qrow] = l_i[g];
      }
    }
  }
}

// ---------------------------------------------------------------------------
// Combine partials for m >= 2. One thread per (head, m, row, d).
__global__ __launch_bounds__(256) void attn_combine(
    const f16* __restrict__ Opart, const float* __restrict__ ml,
    f16* __restrict__ out) {
  int idx = blockIdx.x * 256 + threadIdx.x;
  int d = idx & 63;
  int row = (idx >> 6) & 127;
  int rest = idx >> 13;      // 0..223
  int mi = rest % 14;        // m-2
  int h = rest / 14;
  int m = 2 + mi;
  int nc = (2 * m + 5) >> 2;
  int base = 0;
  for (int j = 2; j < m; j++) base += (2 * j + 5) >> 2;
  int slot0 = h * 70 + base;

  float M = -1e30f;
  for (int cc = 0; cc < nc; cc++)
    M = fmaxf(M, ml[(slot0 + cc) * 256 + row]);
  float L = 0.f, acc = 0.f;
  for (int cc = 0; cc < nc; cc++) {
    float w = exp2f(ml[(slot0 + cc) * 256 + row] - M);
    L += w * ml[(slot0 + cc) * 256 + 128 + row];
    acc += w * (float)Opart[(size_t)(slot0 + cc) * 8192 + row * 64 + d];
  }
  out[(size_t)(m * 128 + row) * HID + h * HDIM + d] = (f16)(acc / L);
}

// ---------------------------------------------------------------------------
extern "C" void kernel_launch(void* const* d_in, const int* in_sizes, int n_in,
                              void* d_out, int out_size, void* d_ws,
                              size_t ws_size, hipStream_t stream) {
  const float* h = (const float*)d_in[0];    // [2048,1024]
  const float* wa = (const float*)d_in[1];   // [1024,3072]
  const float* ba = (const float*)d_in[2];   // [3072]
  const float* wp = (const float*)d_in[3];   // [1024,1024]
  const float* bp = (const float*)d_in[4];   // [1024]
  float* out = (float*)d_out;                // [2048,1024] fp32

  char* ws = (char*)d_ws;
  f16* waT = (f16*)(ws);                       //  6 MiB [3072][1024]
  f16* wpT = (f16*)(ws + (6u << 20));          //  2 MiB [1024][1024]
  f16* qkv = (f16*)(ws + (8u << 20));          // 12 MiB [2048][3072]
  f16* attn = (f16*)(ws + (20u << 20));        //  4 MiB [2048][1024]
  f16* Opart = (f16*)(ws + (24u << 20));       // 1120*8192*2 = 18.35 MB
  float* mlbuf = (float*)(ws + (24u << 20) + 18350080);  // 1120*256*4

  prologue<<<4096, 256, 0, stream>>>(wa, wp, waT, wpT);
  // QKV = H @ Wattn + b -> f16 (fp32 cast fused); 128x64 tiles, 768 blocks
  gemm_f16<128, 64, true, true><<<dim3(48, 16), 256, 0, stream>>>(
      h, waT, ba, qkv, SEQ, 3 * HID, HID);
  // split-K causal attention (chunk=4, 1152 blocks) + combine
  attn_split<<<1152, 256, 0, stream>>>(qkv, attn, Opart, mlbuf);
  attn_combine<<<7168, 256, 0, stream>>>(Opart, mlbuf, attn);
  // OUT = attn @ Wproj + b -> fp32 ; 64x64 tiles, 512 blocks
  gemm_f16<64, 64, false, false><<<dim3(16, 32), 256, 0, stream>>>(
      attn, wpT, bp, out, SEQ, HID, HID);
}

// Round 7
// 162.907 us; speedup vs baseline: 1.1945x; 1.0820x over previous
//
#include <hip/hip_runtime.h>
#include <cstdint>
#include <cstddef>

// Problem constants
#define SEQ 2048
#define HID 1024
#define NHEAD 16
#define HDIM 64

typedef _Float16 f16;
typedef f16 half8 __attribute__((ext_vector_type(8)));
typedef f16 half4 __attribute__((ext_vector_type(4)));
typedef float f32x4 __attribute__((ext_vector_type(4)));

// async global->LDS, 16B per lane (wave-uniform LDS base + lane*16)
#define ASYNC_COPY16(g, l)                                                    \
  __builtin_amdgcn_global_load_lds(                                           \
      (const __attribute__((address_space(1))) void*)(const void*)(g),        \
      (__attribute__((address_space(3))) void*)(void*)(l), 16, 0, 0)

// ---------------------------------------------------------------------------
// Merged prologue: [0,3072) transpose-cast w_attn, [3072,4096) transpose-cast
// w_proj, [4096,6144) cast hidden fp32->f16.
__global__ __launch_bounds__(256) void prologue(
    const float* __restrict__ h, const float* __restrict__ wa,
    const float* __restrict__ wp, f16* __restrict__ h16,
    f16* __restrict__ waT, f16* __restrict__ wpT) {
  const int b = blockIdx.x, tid = threadIdx.x;
  if (b >= 4096) {  // cast h
    int i = ((b - 4096) * 256 + tid) * 4;
    float4 v = *(const float4*)(h + i);
    half4 o;
    o[0] = (f16)v.x; o[1] = (f16)v.y; o[2] = (f16)v.z; o[3] = (f16)v.w;
    *(half4*)(h16 + i) = o;
    return;
  }
  const float* src; f16* dst; int C, bx, by;
  if (b < 3072) { src = wa; dst = waT; C = 3072; bx = b % 96; by = b / 96; }
  else { int t = b - 3072; src = wp; dst = wpT; C = 1024; bx = t & 31; by = t >> 5; }
  __shared__ float tile[32][33];
  const int tx = tid & 31, ty = tid >> 5;  // 32 x 8
  const int c0 = bx * 32, r0 = by * 32;
#pragma unroll
  for (int i = 0; i < 32; i += 8)
    tile[ty + i][tx] = src[(size_t)(r0 + ty + i) * C + c0 + tx];
  __syncthreads();
#pragma unroll
  for (int i = 0; i < 32; i += 8)
    dst[(size_t)(c0 + ty + i) * 1024 + r0 + tx] = (f16)tile[tx][ty + i];
}

// ---------------------------------------------------------------------------
// C = A[M,K](f16) * Bt[N,K]^T + bias ; BM x BN tile, two BK=32 sub-tiles per
// barrier pair (K-step 64), async global_load_lds staging throughout.
template <int BM, int BN, bool OUT16>
__global__ __launch_bounds__(256) void gemm_f16(
    const f16* __restrict__ A, const f16* __restrict__ Bt,
    const float* __restrict__ bias, void* __restrict__ Cout, int M, int N,
    int K) {
  constexpr int FM = BM / 32, FN = BN / 32;
  __shared__ __align__(16) f16 sA[2][BM * 32];
  __shared__ __align__(16) f16 sB[2][BN * 32];
  const int tid = threadIdx.x;
  const int wave = tid >> 6, lane = tid & 63;
  const int quad = lane >> 4, l16 = lane & 15;
  const int m0 = blockIdx.y * BM, n0 = blockIdx.x * BN;
  const int wm = (wave >> 1) * (BM / 2), wn = (wave & 1) * (BN / 2);
  const int rowA = lane >> 2, chunkA = lane & 3;

  f32x4 acc[FM][FN] = {};

  for (int k0 = 0; k0 < K; k0 += 64) {
#pragma unroll
    for (int tt = 0; tt < 2; tt++) {
#pragma unroll
      for (int r = wave; r < BM / 16; r += 4)
        ASYNC_COPY16(
            A + (size_t)(m0 + r * 16 + rowA) * K + k0 + tt * 32 + chunkA * 8,
            &sA[tt][r * 512]);
#pragma unroll
      for (int r = wave; r < BN / 16; r += 4)
        ASYNC_COPY16(
            Bt + (size_t)(n0 + r * 16 + rowA) * K + k0 + tt * 32 + chunkA * 8,
            &sB[tt][r * 512]);
    }
    __syncthreads();

#pragma unroll
    for (int tt = 0; tt < 2; tt++) {
      half8 af[FM], bf[FN];
#pragma unroll
      for (int i = 0; i < FM; i++)
        af[i] = *(const half8*)&sA[tt][(wm + i * 16 + l16) * 32 + quad * 8];
#pragma unroll
      for (int j = 0; j < FN; j++)
        bf[j] = *(const half8*)&sB[tt][(wn + j * 16 + l16) * 32 + quad * 8];
#pragma unroll
      for (int i = 0; i < FM; i++)
#pragma unroll
        for (int j = 0; j < FN; j++)
          acc[i][j] = __builtin_amdgcn_mfma_f32_16x16x32_f16(af[i], bf[j],
                                                             acc[i][j], 0, 0, 0);
    }
    __syncthreads();
  }

#pragma unroll
  for (int i = 0; i < FM; i++) {
    int row = m0 + wm + i * 16 + quad * 4;
#pragma unroll
    for (int j = 0; j < FN; j++) {
      int col = n0 + wn + j * 16 + l16;
      float bv = bias[col];
#pragma unroll
      for (int r = 0; r < 4; r++) {
        float v = acc[i][j][r] + bv;
        if (OUT16)
          ((f16*)Cout)[(size_t)(row + r) * N + col] = (f16)v;
        else
          ((float*)Cout)[(size_t)(row + r) * N + col] = v;
      }
    }
  }
}

// ---------------------------------------------------------------------------
// Split-K causal flash attention (LDS-staged, chunk=4).
// Transposed-S: lane owns one q-column; 32 q-rows/wave (2 groups share K/V
// frags). 128 q-rows/block. Grid: 16 heads x 72 (m,chunk) = 1152 blocks.
#define LROW 72
__global__ __launch_bounds__(256, 3) void attn_split(
    const f16* __restrict__ qkv, f16* __restrict__ out,
    f16* __restrict__ Opart, float* __restrict__ ml) {
  const int b = blockIdx.x;
  const int h = b / 72;
  const int t = b % 72;
  int m, c, nc, base = 0;
  if (t < 2) { m = t; c = 0; nc = 1; }
  else {
    int s = t - 2, acc = 0;
    m = 2; c = 0; nc = 2;
    for (int mm = 2; mm <= 15; mm++) {
      int n = (2 * mm + 5) >> 2;  // ceil((2m+2)/4)
      if (s < acc + n) { m = mm; c = s - acc; nc = n; base = acc; break; }
      acc += n;
    }
  }
  const int q0 = m * 128;
  const int T = 2 * m + 2;             // k64 tiles (causal)
  const int kt0 = c * 4;
  const int kt1 = (kt0 + 4 < T) ? kt0 + 4 : T;
  const int maskFrom = 2 * m;

  __shared__ __align__(16) f16 sK[64 * LROW];      // [s_k][d]
  __shared__ __align__(16) f16 sVt[64 * LROW];     // [d][s_k]
  __shared__ __align__(16) f16 sP[4][32 * LROW];   // per-wave P[q][k]

  const int tid = threadIdx.x;
  const int wave = tid >> 6, lane = tid & 63;
  const int quad = lane >> 4, l16 = lane & 15;

  // Q fragments (MFMA B operand), pre-scaled by sm_scale*log2(e)
  const f16 qs = (f16)0.18033688f;  // 0.125 * log2(e)
  half8 qf[2][2];
#pragma unroll
  for (int g = 0; g < 2; g++) {
    const f16* qb = qkv + (size_t)(q0 + wave * 32 + g * 16 + l16) * 3072 +
                    h * HDIM + quad * 8;
    qf[g][0] = *(const half8*)qb;
    qf[g][1] = *(const half8*)(qb + 32);
#pragma unroll
    for (int j = 0; j < 8; j++) { qf[g][0][j] *= qs; qf[g][1][j] *= qs; }
  }

  const f16* kbase = qkv + HID + h * HDIM;
  const f16* vbase = qkv + 2 * HID + h * HDIM;
  const int ks_row = tid >> 3, ks_cc = tid & 7;
  const int vs_d = tid & 63, vs_g = tid >> 6;

  f32x4 o[2][4] = {};
  float m_i[2] = {-1e30f, -1e30f}, l_i[2] = {0.f, 0.f};
  half8 kreg[2], vreg[2];

  auto prefetch = [&](int kt) {
    const int k0 = kt * 64;
#pragma unroll
    for (int i = 0; i < 2; i++) {
      kreg[i] = *(const half8*)(kbase + (size_t)(k0 + ks_row + i * 32) * 3072 +
                                ks_cc * 8);
      half8 col;
#pragma unroll
      for (int j = 0; j < 8; j++)
        col[j] = vbase[(size_t)(k0 + (vs_g + i * 4) * 8 + j) * 3072 + vs_d];
      vreg[i] = col;
    }
  };

  prefetch(kt0);
  for (int kt = kt0; kt < kt1; kt++) {
    const int k0 = kt * 64;
#pragma unroll
    for (int i = 0; i < 2; i++) {
      *(half8*)&sK[(ks_row + i * 32) * LROW + ks_cc * 8] = kreg[i];
      *(half8*)&sVt[vs_d * LROW + (vs_g + i * 4) * 8] = vreg[i];
    }
    __syncthreads();
    if (kt + 1 < kt1) prefetch(kt + 1);

    // S^T = K Q^T ; K-frag reads shared across both q-groups
    f32x4 sacc[2][4] = {};
#pragma unroll
    for (int kb = 0; kb < 4; kb++) {
      half8 kf0 = *(const half8*)&sK[(kb * 16 + l16) * LROW + quad * 8];
      half8 kf1 = *(const half8*)&sK[(kb * 16 + l16) * LROW + 32 + quad * 8];
#pragma unroll
      for (int g = 0; g < 2; g++) {
        sacc[g][kb] = __builtin_amdgcn_mfma_f32_16x16x32_f16(kf0, qf[g][0],
                                                             sacc[g][kb], 0, 0, 0);
        sacc[g][kb] = __builtin_amdgcn_mfma_f32_16x16x32_f16(kf1, qf[g][1],
                                                             sacc[g][kb], 0, 0, 0);
      }
    }
    // causal mask on diagonal-overlap tiles
    if (kt >= maskFrom) {
#pragma unroll
      for (int g = 0; g < 2; g++) {
        const int qg = q0 + wave * 32 + g * 16 + l16;
#pragma unroll
        for (int kb = 0; kb < 4; kb++) {
          int kg = k0 + kb * 16 + quad * 4;
#pragma unroll
          for (int r = 0; r < 4; r++)
            if (kg + r > qg) sacc[g][kb][r] = -1e30f;
        }
      }
    }
    // online softmax per q-group (lane owns one q-column per group)
#pragma unroll
    for (int g = 0; g < 2; g++) {
      float mx = -1e30f;
#pragma unroll
      for (int kb = 0; kb < 4; kb++)
#pragma unroll
        for (int r = 0; r < 4; r++) mx = fmaxf(mx, sacc[g][kb][r]);
      mx = fmaxf(mx, __shfl_xor(mx, 16));
      mx = fmaxf(mx, __shfl_xor(mx, 32));
      const float mnew = fmaxf(m_i[g], mx);
      const float alpha = exp2f(m_i[g] - mnew);
      float rs = 0.f;
#pragma unroll
      for (int kb = 0; kb < 4; kb++)
#pragma unroll
        for (int r = 0; r < 4; r++) {
          float p = exp2f(sacc[g][kb][r] - mnew);
          sacc[g][kb][r] = p;
          rs += p;
        }
      rs += __shfl_xor(rs, 16);
      rs += __shfl_xor(rs, 32);
      l_i[g] = l_i[g] * alpha + rs;
      m_i[g] = mnew;
#pragma unroll
      for (int j = 0; j < 4; j++)
#pragma unroll
        for (int r = 0; r < 4; r++) o[g][j][r] *= alpha;
      // P store: one b64 per kb (quad*4 consecutive k values)
      f16* pw = &sP[wave][(g * 16 + l16) * LROW];
#pragma unroll
      for (int kb = 0; kb < 4; kb++) {
        half4 pv;
#pragma unroll
        for (int r = 0; r < 4; r++) pv[r] = (f16)sacc[g][kb][r];
        *(half4*)&pw[kb * 16 + quad * 4] = pv;
      }
    }
    // O^T += V^T P^T ; V-frag reads shared across both q-groups
#pragma unroll
    for (int j = 0; j < 4; j++) {
      half8 vf0 = *(const half8*)&sVt[(j * 16 + l16) * LROW + quad * 8];
      half8 vf1 = *(const half8*)&sVt[(j * 16 + l16) * LROW + 32 + quad * 8];
#pragma unroll
      for (int g = 0; g < 2; g++) {
        half8 pf0 = *(const half8*)&sP[wave][(g * 16 + l16) * LROW + quad * 8];
        half8 pf1 =
            *(const half8*)&sP[wave][(g * 16 + l16) * LROW + 32 + quad * 8];
        o[g][j] = __builtin_amdgcn_mfma_f32_16x16x32_f16(vf0, pf0, o[g][j], 0, 0, 0);
        o[g][j] = __builtin_amdgcn_mfma_f32_16x16x32_f16(vf1, pf1, o[g][j], 0, 0, 0);
      }
    }
    __syncthreads();
  }

  if (nc == 1) {
#pragma unroll
    for (int g = 0; g < 2; g++) {
      const float inv = 1.f / l_i[g];
      f16* orow =
          out + (size_t)(q0 + wave * 32 + g * 16 + l16) * HID + h * HDIM;
#pragma unroll
      for (int j = 0; j < 4; j++) {
        half4 hv;
#pragma unroll
        for (int r = 0; r < 4; r++) hv[r] = (f16)(o[g][j][r] * inv);
        *(half4*)&orow[j * 16 + quad * 4] = hv;
      }
    }
  } else {
    const int slot = h * 70 + base + c;  // 70 multi-chunk slots per head
#pragma unroll
    for (int g = 0; g < 2; g++) {
      const int qrow = wave * 32 + g * 16 + l16;
      f16* op = Opart + (size_t)slot * 8192 + qrow * 64;
#pragma unroll
      for (int j = 0; j < 4; j++) {
        half4 hv;
#pragma unroll
        for (int r = 0; r < 4; r++) hv[r] = (f16)o[g][j][r];
        *(half4*)&op[j * 16 + quad * 4] = hv;
      }
      if (quad == 0) {
        ml[slot * 256 + qrow] = m_i[g];
        ml[slot * 256 + 128 + qrow] = l_i[g];
      }
    }
  }
}

// ---------------------------------------------------------------------------
// Combine partials for m >= 2. One thread per (head, m, row, d).
__global__ __launch_bounds__(256) void attn_combine(
    const f16* __restrict__ Opart, const float* __restrict__ ml,
    f16* __restrict__ out) {
  int idx = blockIdx.x * 256 + threadIdx.x;
  int d = idx & 63;
  int row = (idx >> 6) & 127;
  int rest = idx >> 13;      // 0..223
  int mi = rest % 14;        // m-2
  int h = rest / 14;
  int m = 2 + mi;
  int nc = (2 * m + 5) >> 2;
  int base = 0;
  for (int j = 2; j < m; j++) base += (2 * j + 5) >> 2;
  int slot0 = h * 70 + base;

  float M = -1e30f;
  for (int cc = 0; cc < nc; cc++)
    M = fmaxf(M, ml[(slot0 + cc) * 256 + row]);
  float L = 0.f, acc = 0.f;
  for (int cc = 0; cc < nc; cc++) {
    float w = exp2f(ml[(slot0 + cc) * 256 + row] - M);
    L += w * ml[(slot0 + cc) * 256 + 128 + row];
    acc += w * (float)Opart[(size_t)(slot0 + cc) * 8192 + row * 64 + d];
  }
  out[(size_t)(m * 128 + row) * HID + h * HDIM + d] = (f16)(acc / L);
}

// ---------------------------------------------------------------------------
extern "C" void kernel_launch(void* const* d_in, const int* in_sizes, int n_in,
                              void* d_out, int out_size, void* d_ws,
                              size_t ws_size, hipStream_t stream) {
  const float* h = (const float*)d_in[0];    // [2048,1024]
  const float* wa = (const float*)d_in[1];   // [1024,3072]
  const float* ba = (const float*)d_in[2];   // [3072]
  const float* wp = (const float*)d_in[3];   // [1024,1024]
  const float* bp = (const float*)d_in[4];   // [1024]
  float* out = (float*)d_out;                // [2048,1024] fp32

  char* ws = (char*)d_ws;
  f16* h16 = (f16*)(ws);                       //  4 MiB
  f16* waT = (f16*)(ws + (4u << 20));          //  6 MiB [3072][1024]
  f16* wpT = (f16*)(ws + (10u << 20));         //  2 MiB [1024][1024]
  f16* qkv = (f16*)(ws + (12u << 20));         // 12 MiB [2048][3072]
  f16* attn = (f16*)(ws + (24u << 20));        //  4 MiB [2048][1024]
  f16* Opart = (f16*)(ws + (28u << 20));       // 1120*8192*2 = 18.35 MB
  float* mlbuf = (float*)(ws + (28u << 20) + 18350080);  // 1120*256*4

  prologue<<<6144, 256, 0, stream>>>(h, wa, wp, h16, waT, wpT);
  // QKV = H @ Wattn + b -> f16 ; 128x128 tiles, K-step 64, 384 blocks
  gemm_f16<128, 128, true><<<dim3(24, 16), 256, 0, stream>>>(
      h16, waT, ba, qkv, SEQ, 3 * HID, HID);
  // split-K causal attention (chunk=4, 1152 blocks) + combine
  attn_split<<<1152, 256, 0, stream>>>(qkv, attn, Opart, mlbuf);
  attn_combine<<<7168, 256, 0, stream>>>(Opart, mlbuf, attn);
  // OUT = attn @ Wproj + b -> fp32 ; 64x64 tiles, K-step 64, 512 blocks
  gemm_f16<64, 64, false><<<dim3(16, 32), 256, 0, stream>>>(
      attn, wpT, bp, out, SEQ, HID, HID);
}